// Round 20
// baseline (132.538 us; speedup 1.0000x reference)
//
#include <hip/hip_runtime.h>

#define N_PRED 25200
#define CONF 0.25f
#define IOU_THR 0.45f
#define MAXD 300
#define IMGW 640
#define CROPW 64
#define HISTN 16640
#define KSPLIT 16

typedef float f32x4 __attribute__((ext_vector_type(4)));
typedef short s16x8 __attribute__((ext_vector_type(8)));
typedef unsigned long long u64;

// ---- workspace layout (bytes) ----
#define OFF_HIST   0u            // 16640*4 = 66560
#define OFF_CNT    66560u        // counters (cnt at +0)
#define OFF_CAND   66816u        // 1024 * 8 = 8192
#define CTRL_BYTES 75008u        // memset [0, CTRL_BYTES) each call
#define OFF_BOXES  75008u        // 300*4*4
#define OFF_XY1    79872u        // 300*2*4
#define OFF_VALID  82432u        // 300*4
#define OFF_KEEP   83712u        // 300*4
#define OFF_SUP    84992u        // 300*5*8 = 12000
#define OFF_FEATS  1325824u      // 320*16384*2 = 10485760
#define OFF_PART   11811584u     // 16*8*320*128*4 = 26214400 (ends ~38MB)

__device__ inline unsigned short f2bf(float x) {
  unsigned u = __float_as_uint(x);
  u += 0x7FFFu + ((u >> 16) & 1u);   // round-to-nearest-even
  return (unsigned short)(u >> 16);
}

// ---------------- stage 1: score histogram (radix cut for top-300) -------
__global__ __launch_bounds__(256) void k_hist(const float* __restrict__ preds,
                                              unsigned* __restrict__ hist) {
  int i = blockIdx.x * 256 + threadIdx.x;
  if (i >= N_PRED) return;
  float s = preds[i * 6 + 4] * preds[i * 6 + 5];
  if (s > CONF) atomicAdd(&hist[__float_as_uint(s) >> 16], 1u);
}

// compact with INLINE findcut: every block recomputes the radix cut from
// hist (deterministic; parallel across blocks), then compacts its slice.
__global__ __launch_bounds__(256) void k_compact(const float* __restrict__ preds,
                                                 const unsigned* __restrict__ hist,
                                                 unsigned* __restrict__ cnt,
                                                 u64* __restrict__ cand) {
  __shared__ unsigned s[256];
  __shared__ unsigned scut;
  int t = threadIdx.x;
  int base = t * 65;                       // 256*65 = 16640
  unsigned local = 0;
  for (int i = 0; i < 65; ++i) local += hist[base + i];
  s[t] = local;
  __syncthreads();
  for (int off = 1; off < 256; off <<= 1) {   // inclusive suffix scan
    unsigned add = (t + off < 256) ? s[t + off] : 0u;
    __syncthreads();
    s[t] += add;
    __syncthreads();
  }
  unsigned incl = s[t];
  unsigned excl = (t < 255) ? s[t + 1] : 0u;
  if (t == 0) scut = 0u;
  __syncthreads();
  if (incl >= (unsigned)MAXD && excl < (unsigned)MAXD) {   // unique owner
    unsigned acc = excl, res = 0u;
    #pragma unroll
    for (int ii = 64; ii >= 0; --ii) {
      acc += hist[base + ii];
      if (res == 0u && acc >= (unsigned)MAXD) res = (unsigned)(base + ii);
    }
    scut = res;
  }
  __syncthreads();
  unsigned cutv = scut;

  int i = blockIdx.x * 256 + t;
  if (i >= N_PRED) return;
  float sc = preds[i * 6 + 4] * preds[i * 6 + 5];
  if (sc <= CONF) return;
  unsigned bits = __float_as_uint(sc);
  if ((bits >> 16) < cutv) return;
  unsigned pos = atomicAdd(cnt, 1u);
  if (pos < 1024u)
    cand[pos] = ((u64)bits << 32) | (u64)(0xFFFFFFFFu - (unsigned)i);  // ties: lower idx first
}

// RANK-based top-300 selection (replaces 55-stage bitonic: 2 barriers).
// Keys unique -> rank = #{j: key_j > key_i} is a bijection; winner threads
// (key!=0, rank<300) write slot `rank` directly. Defaults pre-written.
__global__ __launch_bounds__(1024) void k_sortprep(const float* __restrict__ preds,
                                                   const u64* __restrict__ cand,
                                                   float* __restrict__ boxes,
                                                   int* __restrict__ xy1,
                                                   float* __restrict__ validf) {
  __shared__ u64 sk[1024];
  int t = threadIdx.x;
  sk[t] = cand[t];
  // defaults for all 300 slots (overwritten by winners after barrier)
  if (t < MAXD) {
    boxes[t * 4 + 0] = 0.f; boxes[t * 4 + 1] = 0.f;
    boxes[t * 4 + 2] = 0.f; boxes[t * 4 + 3] = 0.f;
    xy1[t * 2 + 0] = 0; xy1[t * 2 + 1] = 0;
    validf[t] = 0.f;
  }
  __syncthreads();
  u64 key = sk[t];
  int rank = 0;
  #pragma unroll 8
  for (int j = 0; j < 1024; ++j)
    rank += (sk[j] > key) ? 1 : 0;           // broadcast LDS reads
  __syncthreads();                           // defaults globally ordered
  if (key != 0ull && rank < MAXD) {
    int idx = (int)(0xFFFFFFFFu - (unsigned)(key & 0xFFFFFFFFull));
    float cx = preds[idx * 6 + 0], cy = preds[idx * 6 + 1];
    float w  = preds[idx * 6 + 2], h  = preds[idx * 6 + 3];
    float x1 = cx - w * 0.5f, y1 = cy - h * 0.5f;
    float x2 = cx + w * 0.5f, y2 = cy + h * 0.5f;
    boxes[rank * 4 + 0] = x1; boxes[rank * 4 + 1] = y1;
    boxes[rank * 4 + 2] = x2; boxes[rank * 4 + 3] = y2;
    int xi = (int)rintf(x1); xi = min(max(xi, 0), IMGW - CROPW);
    int yi = (int)rintf(y1); yi = min(max(yi, 0), IMGW - CROPW);
    xy1[rank * 2 + 0] = xi; xy1[rank * 2 + 1] = yi;
    validf[rank] = 1.0f;
  }
}

// parallel IoU suppression-mask build: block i = row i, thread t = column.
__global__ __launch_bounds__(320) void k_iou(const float* __restrict__ boxes,
                                             u64* __restrict__ sup) {
  int i = blockIdx.x, t = threadIdx.x;
  int w = t >> 6, lane = t & 63;
  f32x4 bi = *(const f32x4*)&boxes[i * 4];           // broadcast
  f32x4 bj = (t < MAXD) ? *(const f32x4*)&boxes[t * 4]
                        : (f32x4){0.f, 0.f, 0.f, 0.f};
  float ar  = (bi[2] - bi[0]) * (bi[3] - bi[1]);
  float arj = (bj[2] - bj[0]) * (bj[3] - bj[1]);
  float iw = fmaxf(fminf(bi[2], bj[2]) - fmaxf(bi[0], bj[0]), 0.f);
  float ih = fmaxf(fminf(bi[3], bj[3]) - fmaxf(bi[1], bj[1]), 0.f);
  float inter = iw * ih;
  float iou = inter / (ar + arj - inter + 1e-7f);
  u64 bm = __ballot((t < MAXD) && (iou > IOU_THR));
  if (lane == 0) sup[i * 5 + w] = bm;
}

// sequential greedy NMS, 1 wave: masks prefetched into registers, ff1 chain.
__global__ __launch_bounds__(64) void k_nms(const u64* __restrict__ sup,
                                            const float* __restrict__ validf,
                                            float* __restrict__ keepf) {
  int lane = threadIdx.x;
  u64 srow[5][5];
  #pragma unroll
  for (int c = 0; c < 5; ++c)
    #pragma unroll
    for (int ww = 0; ww < 5; ++ww) srow[c][ww] = 0ull;
  #pragma unroll
  for (int c = 0; c < 5; ++c) {
    int i = c * 64 + lane;
    if (i < MAXD) {
      #pragma unroll
      for (int ww = 0; ww <= c; ++ww) srow[c][ww] = sup[i * 5 + ww];
    }
  }
  u64 validm[5];
  #pragma unroll
  for (int c = 0; c < 5; ++c) {
    int i = c * 64 + lane;
    float vf = (i < MAXD) ? validf[i] : 0.f;
    validm[c] = __ballot(vf > 0.5f);
  }
  u64 kw0 = 0, kw1 = 0, kw2 = 0, kw3 = 0;
  #pragma unroll
  for (int c = 0; c < 5; ++c) {
    bool ext = ((srow[c][0] & kw0) | (srow[c][1] & kw1) |
                (srow[c][2] & kw2) | (srow[c][3] & kw3)) != 0ull;
    u64 alive = validm[c] & __ballot(!ext);
    unsigned mlo = (unsigned)srow[c][c], mhi = (unsigned)(srow[c][c] >> 32);
    u64 rem = alive;
    while (rem) {                           // rolled: only alive bits
      int b = (int)__builtin_ctzll(rem);
      u64 gt = (b == 63) ? 0ull : (~0ull << (b + 1));
      u64 mi = ((u64)(unsigned)__builtin_amdgcn_readlane((int)mhi, b) << 32) |
               (u64)(unsigned)__builtin_amdgcn_readlane((int)mlo, b);
      alive &= ~(mi & gt);
      rem = alive & gt;
    }
    int i = c * 64 + lane;
    if (i < MAXD) keepf[i] = ((alive >> lane) & 1ull) ? 1.f : 0.f;
    if (c == 0) kw0 = alive;
    else if (c == 1) kw1 = alive;
    else if (c == 2) kw2 = alive;
    else if (c == 3) kw3 = alive;
  }
}

// crop + 3x3 SAME conv(16) + ReLU + 2x2 maxpool -> feats[det][16384] (bf16)
// Grid (300, 8): det x 4-pooled-row slice. 256 thr = (ch 0..15) x (px 0..15).
__global__ __launch_bounds__(256) void k_cropconv(const float* __restrict__ image,
                                                  const float* __restrict__ Wc,
                                                  const float* __restrict__ bc,
                                                  const int* __restrict__ xy1,
                                                  short* __restrict__ feats) {
  __shared__ __align__(16) float crop[3][10][68];   // 8160 B
  int det = blockIdx.x, sl = blockIdx.y, tid = threadIdx.x;
  int pr0 = sl * 4;                 // pooled rows pr0..pr0+3
  int gyBase = pr0 * 2 - 1;         // global crop row of local ry=0 (10 rows)
  int ch = tid >> 4, px = tid & 15;

  float w[27];
  #pragma unroll
  for (int i = 0; i < 27; i++) w[i] = Wc[ch * 27 + i];
  float bias = bc[ch];

  int x0 = xy1[det * 2 + 0], y0 = xy1[det * 2 + 1];
  // register-stage 3*10*64 = 1920 elements (8 rounds of 256)
  float sv[8];
  #pragma unroll
  for (int i = 0; i < 8; i++) {
    int u = tid + i * 256;
    float v = 0.f;
    if (u < 1920) {
      int row = u >> 6, x = u & 63;
      int c = row / 10, ry = row - c * 10;
      int gy = gyBase + ry;
      if (gy >= 0 && gy < CROPW)
        v = image[(size_t)c * (IMGW * IMGW) + (y0 + gy) * IMGW + x0 + x];
    }
    sv[i] = v;
  }
  // zero the never-staged edge cells: cols {0,65,66,67} x 30 rows = 120
  if (tid < 120) {
    int row = tid >> 2, e = tid & 3;
    int c = row / 10, ry = row - c * 10;
    crop[c][ry][(e == 0) ? 0 : (64 + e)] = 0.f;
  }
  #pragma unroll
  for (int i = 0; i < 8; i++) {
    int u = tid + i * 256;
    if (u < 1920) {
      int row = u >> 6, x = u & 63;
      int c = row / 10, ry = row - c * 10;
      crop[c][ry][x + 1] = sv[i];
    }
  }
  __syncthreads();
  #pragma unroll
  for (int pr = 0; pr < 4; pr++) {
    float acc0[4] = {0.f, 0.f, 0.f, 0.f};
    float acc1[4] = {0.f, 0.f, 0.f, 0.f};
    #pragma unroll
    for (int c = 0; c < 3; c++) {
      #pragma unroll
      for (int r = 0; r < 4; r++) {
        const float* rp = &crop[c][2 * pr + r][4 * px];
        f32x4 v4 = *(const f32x4*)rp;               // 16B-aligned b128
        float2 v2 = *(const float2*)(rp + 4);       // 16B-aligned b64
        float in[6] = {v4[0], v4[1], v4[2], v4[3], v2.x, v2.y};
        if (r <= 2) {                               // conv row 0, kernel row r
          const float w0 = w[c * 9 + r * 3], w1 = w[c * 9 + r * 3 + 1],
                      w2 = w[c * 9 + r * 3 + 2];
          #pragma unroll
          for (int q = 0; q < 4; q++)
            acc0[q] += in[q] * w0 + in[q + 1] * w1 + in[q + 2] * w2;
        }
        if (r >= 1) {                               // conv row 1, kernel row r-1
          const float w0 = w[c * 9 + (r - 1) * 3], w1 = w[c * 9 + (r - 1) * 3 + 1],
                      w2 = w[c * 9 + (r - 1) * 3 + 2];
          #pragma unroll
          for (int q = 0; q < 4; q++)
            acc1[q] += in[q] * w0 + in[q + 1] * w1 + in[q + 2] * w2;
        }
      }
    }
    float m0 = fmaxf(fmaxf(acc0[0], acc0[1]), fmaxf(acc1[0], acc1[1]));
    float m1 = fmaxf(fmaxf(acc0[2], acc0[3]), fmaxf(acc1[2], acc1[3]));
    unsigned lo = f2bf(fmaxf(m0 + bias, 0.f));
    unsigned hi = f2bf(fmaxf(m1 + bias, 0.f));
    *(unsigned*)&feats[(size_t)det * 16384 + ch * 1024 + (pr0 + pr) * 32 + 2 * px] =
        lo | (hi << 16);
  }
}

// Fused FC1 GEMM (r10 structure -- best measured: 42us)
__global__ __launch_bounds__(512, 2) void k_gemm(const short* __restrict__ feats,
                                                 const float* __restrict__ W1,
                                                 float* __restrict__ part) {
  __shared__ __align__(16) short As[2][320 * 64];   // 81920 B
  int tid = threadIdx.x;
  int wid = tid >> 6, lane = tid & 63;
  int wm = wid & 3, wn = wid >> 2;          // 4 m-waves x 2 n-waves
  int lr = lane & 15, kg = lane >> 4;
  int ks = blockIdx.x, hd = blockIdx.y, dh = blockIdx.z;
  const int f0 = ks * 1024, d0 = dh * 64;
  const float* w1h = W1 + (size_t)hd * 16384 * 128;

  f32x4 acc[5][2];
  #pragma unroll
  for (int i = 0; i < 5; i++)
    #pragma unroll
    for (int j = 0; j < 2; j++) acc[i][j] = (f32x4){0.f, 0.f, 0.f, 0.f};

  // prologue: A tile 0 + B tile 0
  s16x8 aR[5];
  #pragma unroll
  for (int i = 0; i < 5; i++) {
    int ch = tid + i * 512, m = ch >> 3, c = ch & 7;
    aR[i] = *(const s16x8*)(feats + (size_t)m * 16384 + f0 + c * 8);
  }
  const float* bp = w1h + (size_t)(f0 + kg * 8) * 128 + d0 + wn * 32 + lr;
  float bF[2][2][8];
  #pragma unroll
  for (int k32 = 0; k32 < 2; k32++)
    #pragma unroll
    for (int nf = 0; nf < 2; nf++)
      #pragma unroll
      for (int j = 0; j < 8; j++)
        bF[k32][nf][j] = bp[(k32 * 32 + j) * 128 + nf * 16];
  #pragma unroll
  for (int i = 0; i < 5; i++) {
    int ch = tid + i * 512, m = ch >> 3, c = ch & 7;
    *(s16x8*)((char*)&As[0][0] + m * 128 + ((c ^ (m & 7)) << 4)) = aR[i];
  }
  __syncthreads();

  for (int t = 0; t < 16; ++t) {
    int cur = t & 1;
    s16x8 bfr[2][2];
    #pragma unroll
    for (int k32 = 0; k32 < 2; k32++)
      #pragma unroll
      for (int nf = 0; nf < 2; nf++)
        #pragma unroll
        for (int j = 0; j < 8; j++)
          bfr[k32][nf][j] = (short)f2bf(bF[k32][nf][j]);
    bool pf = (t + 1) < 16;
    if (pf) {                                 // issue next-tile loads early
      int f1 = f0 + (t + 1) * 64;
      #pragma unroll
      for (int i = 0; i < 5; i++) {
        int ch = tid + i * 512, m = ch >> 3, c = ch & 7;
        aR[i] = *(const s16x8*)(feats + (size_t)m * 16384 + f1 + c * 8);
      }
      const float* bp2 = bp + (size_t)(t + 1) * 64 * 128;
      #pragma unroll
      for (int k32 = 0; k32 < 2; k32++)
        #pragma unroll
        for (int nf = 0; nf < 2; nf++)
          #pragma unroll
          for (int j = 0; j < 8; j++)
            bF[k32][nf][j] = bp2[(k32 * 32 + j) * 128 + nf * 16];
    }
    #pragma unroll
    for (int k32 = 0; k32 < 2; ++k32) {
      s16x8 af[5];
      #pragma unroll
      for (int mf = 0; mf < 5; ++mf) {
        int row = wm * 80 + mf * 16 + lr;
        int c = k32 * 4 + kg;
        af[mf] = *(const s16x8*)((const char*)&As[cur][0] + row * 128 + ((c ^ (row & 7)) << 4));
      }
      #pragma unroll
      for (int nf = 0; nf < 2; ++nf)
        #pragma unroll
        for (int mf = 0; mf < 5; ++mf)
          acc[mf][nf] = __builtin_amdgcn_mfma_f32_16x16x32_bf16(af[mf], bfr[k32][nf], acc[mf][nf], 0, 0, 0);
    }
    if (pf) {                                 // write next tile (other buffer)
      #pragma unroll
      for (int i = 0; i < 5; i++) {
        int ch = tid + i * 512, m = ch >> 3, c = ch & 7;
        *(s16x8*)((char*)&As[cur ^ 1][0] + m * 128 + ((c ^ (m & 7)) << 4)) = aR[i];
      }
      __syncthreads();
    }
  }
  #pragma unroll
  for (int mf = 0; mf < 5; ++mf)
    #pragma unroll
    for (int nf = 0; nf < 2; ++nf)
      #pragma unroll
      for (int r = 0; r < 4; ++r) {
        int m = wm * 80 + mf * 16 + kg * 4 + r;   // C/D: row=(lane>>4)*4+r, col=lane&15
        int d = d0 + wn * 32 + nf * 16 + lr;
        part[(((size_t)ks * 8 + hd) * 320 + m) * 128 + d] = acc[mf][nf][r];
      }
}

// FC2 with inline split-K reduce: block per det; stage h[8][128] into LDS by
// summing 16 ksp partials + bias + relu, then the per-head matvecs.
__global__ __launch_bounds__(320) void k_fc2(const float* __restrict__ part,
                                             const float* __restrict__ b1,
                                             const float* __restrict__ keepf,
                                             const float* __restrict__ W2p,
                                             const float* __restrict__ b2p,
                                             const float* __restrict__ W2a,
                                             const float* __restrict__ b2a,
                                             const float* __restrict__ W2d,
                                             const float* __restrict__ b2d,
                                             float* __restrict__ out) {
  int det = blockIdx.x, t = threadIdx.x;
  __shared__ float hl[1024];
  for (int i = t; i < 1024; i += 320) {
    int hh = i >> 7, d = i & 127;
    float s = 0.f;
    #pragma unroll
    for (int ksp = 0; ksp < KSPLIT; ksp++)
      s += part[(((size_t)ksp * 8 + hh) * 320 + det) * 128 + d];
    hl[i] = fmaxf(s + b1[hh * 128 + d], 0.f);
  }
  __syncthreads();
  if (t >= 273) return;
  float kf = keepf[det];
  float s = 0.f, bias;
  if (t < 38) {
    const float* hp = hl;                        // head 0
    for (int d = 0; d < 128; d++) s += hp[d] * W2p[d * 38 + t];
    bias = b2p[t];
  } else if (t < 63) {
    int c = t - 38;
    const float* hp = hl + 128;                  // head 1
    for (int d = 0; d < 128; d++) s += hp[d] * W2a[d * 25 + c];
    bias = b2a[c];
  } else {
    int u = t - 63, j = u / 35, o = u - j * 35;
    const float* hp = hl + (2 + j) * 128;        // heads 2..7
    for (int d = 0; d < 128; d++) s += hp[d] * W2d[((size_t)j * 128 + d) * 35 + o];
    bias = b2d[j * 35 + o];
  }
  out[det * 273 + t] = (s + bias) * kf;
}

extern "C" void kernel_launch(void* const* d_in, const int* in_sizes, int n_in,
                              void* d_out, int out_size, void* d_ws, size_t ws_size,
                              hipStream_t stream) {
  (void)in_sizes; (void)n_in; (void)out_size; (void)ws_size;
  const float* preds = (const float*)d_in[0];
  const float* image = (const float*)d_in[1];
  const float* Wc    = (const float*)d_in[2];
  const float* bc    = (const float*)d_in[3];
  const float* W1    = (const float*)d_in[4];
  const float* b1    = (const float*)d_in[5];
  const float* W2p   = (const float*)d_in[6];
  const float* b2p   = (const float*)d_in[7];
  const float* W2a   = (const float*)d_in[8];
  const float* b2a   = (const float*)d_in[9];
  const float* W2d   = (const float*)d_in[10];
  const float* b2d   = (const float*)d_in[11];

  char* ws = (char*)d_ws;
  unsigned* hist   = (unsigned*)(ws + OFF_HIST);
  unsigned* cnt    = (unsigned*)(ws + OFF_CNT);
  u64*      cand   = (u64*)(ws + OFF_CAND);
  float*    boxes  = (float*)(ws + OFF_BOXES);
  int*      xy1    = (int*)(ws + OFF_XY1);
  float*    validf = (float*)(ws + OFF_VALID);
  float*    keepf  = (float*)(ws + OFF_KEEP);
  u64*      sup    = (u64*)(ws + OFF_SUP);
  short*    feats  = (short*)(ws + OFF_FEATS);
  float*    part   = (float*)(ws + OFF_PART);
  float*    out    = (float*)d_out;

  hipMemsetAsync(ws, 0, CTRL_BYTES, stream);
  k_hist<<<(N_PRED + 255) / 256, 256, 0, stream>>>(preds, hist);
  k_compact<<<(N_PRED + 255) / 256, 256, 0, stream>>>(preds, hist, cnt, cand);
  k_sortprep<<<1, 1024, 0, stream>>>(preds, cand, boxes, xy1, validf);
  k_iou<<<MAXD, 320, 0, stream>>>(boxes, sup);
  k_nms<<<1, 64, 0, stream>>>(sup, validf, keepf);
  k_cropconv<<<dim3(300, 8), 256, 0, stream>>>(image, Wc, bc, xy1, feats);
  k_gemm<<<dim3(KSPLIT, 8, 2), 512, 0, stream>>>(feats, W1, part);
  k_fc2<<<MAXD, 320, 0, stream>>>(part, b1, keepf, W2p, b2p, W2a, b2a, W2d, b2d, out);
}

// Round 21
// 119.914 us; speedup vs baseline: 1.1053x; 1.1053x over previous
//
#include <hip/hip_runtime.h>

#define N_PRED 25200
#define CONF 0.25f
#define IOU_THR 0.45f
#define MAXD 300
#define IMGW 640
#define CROPW 64
#define HISTN 16640
#define KSPLIT 16

typedef float f32x4 __attribute__((ext_vector_type(4)));
typedef short s16x8 __attribute__((ext_vector_type(8)));
typedef unsigned long long u64;

// ---- workspace layout (bytes) ----
#define OFF_HIST   0u            // 16640*4 = 66560
#define OFF_CNT    66560u        // counters (cnt at +0)
#define OFF_CAND   66816u        // 1024 * 8 = 8192
#define CTRL_BYTES 75008u        // memset [0, CTRL_BYTES) each call
#define OFF_BOXES  75008u        // 300*4*4
#define OFF_XY1    79872u        // 300*2*4
#define OFF_VALID  82432u        // 300*4
#define OFF_KEEP   83712u        // 300*4
#define OFF_SUP    84992u        // 300*5*8 = 12000
#define OFF_FEATS  1325824u      // 320*16384*2 = 10485760
#define OFF_PART   11811584u     // 16*8*320*128*4 = 26214400 (ends ~38MB)

__device__ inline unsigned short f2bf(float x) {
  unsigned u = __float_as_uint(x);
  u += 0x7FFFu + ((u >> 16) & 1u);   // round-to-nearest-even
  return (unsigned short)(u >> 16);
}

// ---------------- stage 1: score histogram (radix cut for top-300) -------
__global__ __launch_bounds__(256) void k_hist(const float* __restrict__ preds,
                                              unsigned* __restrict__ hist) {
  int i = blockIdx.x * 256 + threadIdx.x;
  if (i >= N_PRED) return;
  float s = preds[i * 6 + 4] * preds[i * 6 + 5];
  if (s > CONF) atomicAdd(&hist[__float_as_uint(s) >> 16], 1u);
}

// compact with INLINE findcut: every block recomputes the radix cut from
// hist (deterministic; parallel across blocks), then compacts its slice.
__global__ __launch_bounds__(256) void k_compact(const float* __restrict__ preds,
                                                 const unsigned* __restrict__ hist,
                                                 unsigned* __restrict__ cnt,
                                                 u64* __restrict__ cand) {
  __shared__ unsigned s[256];
  __shared__ unsigned scut;
  int t = threadIdx.x;
  int base = t * 65;                       // 256*65 = 16640
  unsigned local = 0;
  for (int i = 0; i < 65; ++i) local += hist[base + i];
  s[t] = local;
  __syncthreads();
  for (int off = 1; off < 256; off <<= 1) {   // inclusive suffix scan
    unsigned add = (t + off < 256) ? s[t + off] : 0u;
    __syncthreads();
    s[t] += add;
    __syncthreads();
  }
  unsigned incl = s[t];
  unsigned excl = (t < 255) ? s[t + 1] : 0u;
  if (t == 0) scut = 0u;
  __syncthreads();
  if (incl >= (unsigned)MAXD && excl < (unsigned)MAXD) {   // unique owner
    unsigned acc = excl, res = 0u;
    #pragma unroll
    for (int ii = 64; ii >= 0; --ii) {
      acc += hist[base + ii];
      if (res == 0u && acc >= (unsigned)MAXD) res = (unsigned)(base + ii);
    }
    scut = res;
  }
  __syncthreads();
  unsigned cutv = scut;

  int i = blockIdx.x * 256 + t;
  if (i >= N_PRED) return;
  float sc = preds[i * 6 + 4] * preds[i * 6 + 5];
  if (sc <= CONF) return;
  unsigned bits = __float_as_uint(sc);
  if ((bits >> 16) < cutv) return;
  unsigned pos = atomicAdd(cnt, 1u);
  if (pos < 1024u)
    cand[pos] = ((u64)bits << 32) | (u64)(0xFFFFFFFFu - (unsigned)i);  // ties: lower idx first
}

// bitonic sort 1024 u64 descending; emit boxes / crop coords / valid flags
__global__ __launch_bounds__(1024) void k_sortprep(const float* __restrict__ preds,
                                                   const u64* __restrict__ cand,
                                                   float* __restrict__ boxes,
                                                   int* __restrict__ xy1,
                                                   float* __restrict__ validf) {
  __shared__ u64 sk[1024];
  int t = threadIdx.x;
  sk[t] = cand[t];
  __syncthreads();
  for (int k = 2; k <= 1024; k <<= 1)
    for (int j = k >> 1; j > 0; j >>= 1) {
      int p = t ^ j;
      if (p > t) {
        u64 a = sk[t], b = sk[p];
        bool up = ((t & k) == 0);
        bool sw = up ? (a < b) : (a > b);      // descending overall
        if (sw) { sk[t] = b; sk[p] = a; }
      }
      __syncthreads();
    }
  if (t < MAXD) {
    u64 key = sk[t];
    if (key != 0ull) {
      int idx = (int)(0xFFFFFFFFu - (unsigned)(key & 0xFFFFFFFFull));
      float cx = preds[idx * 6 + 0], cy = preds[idx * 6 + 1];
      float w  = preds[idx * 6 + 2], h  = preds[idx * 6 + 3];
      float x1 = cx - w * 0.5f, y1 = cy - h * 0.5f;
      float x2 = cx + w * 0.5f, y2 = cy + h * 0.5f;
      boxes[t * 4 + 0] = x1; boxes[t * 4 + 1] = y1;
      boxes[t * 4 + 2] = x2; boxes[t * 4 + 3] = y2;
      int xi = (int)rintf(x1); xi = min(max(xi, 0), IMGW - CROPW);
      int yi = (int)rintf(y1); yi = min(max(yi, 0), IMGW - CROPW);
      xy1[t * 2 + 0] = xi; xy1[t * 2 + 1] = yi;
      validf[t] = 1.0f;
    } else {
      boxes[t * 4 + 0] = 0.f; boxes[t * 4 + 1] = 0.f;
      boxes[t * 4 + 2] = 0.f; boxes[t * 4 + 3] = 0.f;
      xy1[t * 2 + 0] = 0; xy1[t * 2 + 1] = 0;
      validf[t] = 0.f;
    }
  }
}

// parallel IoU suppression-mask build: block i = row i, thread t = column.
__global__ __launch_bounds__(320) void k_iou(const float* __restrict__ boxes,
                                             u64* __restrict__ sup) {
  int i = blockIdx.x, t = threadIdx.x;
  int w = t >> 6, lane = t & 63;
  f32x4 bi = *(const f32x4*)&boxes[i * 4];           // broadcast
  f32x4 bj = (t < MAXD) ? *(const f32x4*)&boxes[t * 4]
                        : (f32x4){0.f, 0.f, 0.f, 0.f};
  float ar  = (bi[2] - bi[0]) * (bi[3] - bi[1]);
  float arj = (bj[2] - bj[0]) * (bj[3] - bj[1]);
  float iw = fmaxf(fminf(bi[2], bj[2]) - fmaxf(bi[0], bj[0]), 0.f);
  float ih = fmaxf(fminf(bi[3], bj[3]) - fmaxf(bi[1], bj[1]), 0.f);
  float inter = iw * ih;
  float iou = inter / (ar + arj - inter + 1e-7f);
  u64 bm = __ballot((t < MAXD) && (iou > IOU_THR));
  if (lane == 0) sup[i * 5 + w] = bm;
}

// sequential greedy NMS, 1 wave: masks prefetched into registers, ff1 chain.
__global__ __launch_bounds__(64) void k_nms(const u64* __restrict__ sup,
                                            const float* __restrict__ validf,
                                            float* __restrict__ keepf) {
  int lane = threadIdx.x;
  u64 srow[5][5];
  #pragma unroll
  for (int c = 0; c < 5; ++c)
    #pragma unroll
    for (int ww = 0; ww < 5; ++ww) srow[c][ww] = 0ull;
  #pragma unroll
  for (int c = 0; c < 5; ++c) {
    int i = c * 64 + lane;
    if (i < MAXD) {
      #pragma unroll
      for (int ww = 0; ww <= c; ++ww) srow[c][ww] = sup[i * 5 + ww];
    }
  }
  u64 validm[5];
  #pragma unroll
  for (int c = 0; c < 5; ++c) {
    int i = c * 64 + lane;
    float vf = (i < MAXD) ? validf[i] : 0.f;
    validm[c] = __ballot(vf > 0.5f);
  }
  u64 kw0 = 0, kw1 = 0, kw2 = 0, kw3 = 0;
  #pragma unroll
  for (int c = 0; c < 5; ++c) {
    bool ext = ((srow[c][0] & kw0) | (srow[c][1] & kw1) |
                (srow[c][2] & kw2) | (srow[c][3] & kw3)) != 0ull;
    u64 alive = validm[c] & __ballot(!ext);
    unsigned mlo = (unsigned)srow[c][c], mhi = (unsigned)(srow[c][c] >> 32);
    u64 rem = alive;
    while (rem) {                           // rolled: only alive bits
      int b = (int)__builtin_ctzll(rem);
      u64 gt = (b == 63) ? 0ull : (~0ull << (b + 1));
      u64 mi = ((u64)(unsigned)__builtin_amdgcn_readlane((int)mhi, b) << 32) |
               (u64)(unsigned)__builtin_amdgcn_readlane((int)mlo, b);
      alive &= ~(mi & gt);
      rem = alive & gt;
    }
    int i = c * 64 + lane;
    if (i < MAXD) keepf[i] = ((alive >> lane) & 1ull) ? 1.f : 0.f;
    if (c == 0) kw0 = alive;
    else if (c == 1) kw1 = alive;
    else if (c == 2) kw2 = alive;
    else if (c == 3) kw3 = alive;
  }
}

// crop + 3x3 SAME conv(16) + ReLU + 2x2 maxpool -> feats[det][16384] (bf16)
// Grid (300, 8): det x 4-pooled-row slice. 256 thr = (ch 0..15) x (px 0..15).
__global__ __launch_bounds__(256) void k_cropconv(const float* __restrict__ image,
                                                  const float* __restrict__ Wc,
                                                  const float* __restrict__ bc,
                                                  const int* __restrict__ xy1,
                                                  short* __restrict__ feats) {
  __shared__ __align__(16) float crop[3][10][68];   // 8160 B
  int det = blockIdx.x, sl = blockIdx.y, tid = threadIdx.x;
  int pr0 = sl * 4;                 // pooled rows pr0..pr0+3
  int gyBase = pr0 * 2 - 1;         // global crop row of local ry=0 (10 rows)
  int ch = tid >> 4, px = tid & 15;

  float w[27];
  #pragma unroll
  for (int i = 0; i < 27; i++) w[i] = Wc[ch * 27 + i];
  float bias = bc[ch];

  int x0 = xy1[det * 2 + 0], y0 = xy1[det * 2 + 1];
  // register-stage 3*10*64 = 1920 elements (8 rounds of 256)
  float sv[8];
  #pragma unroll
  for (int i = 0; i < 8; i++) {
    int u = tid + i * 256;
    float v = 0.f;
    if (u < 1920) {
      int row = u >> 6, x = u & 63;
      int c = row / 10, ry = row - c * 10;
      int gy = gyBase + ry;
      if (gy >= 0 && gy < CROPW)
        v = image[(size_t)c * (IMGW * IMGW) + (y0 + gy) * IMGW + x0 + x];
    }
    sv[i] = v;
  }
  // zero the never-staged edge cells: cols {0,65,66,67} x 30 rows = 120
  if (tid < 120) {
    int row = tid >> 2, e = tid & 3;
    int c = row / 10, ry = row - c * 10;
    crop[c][ry][(e == 0) ? 0 : (64 + e)] = 0.f;
  }
  #pragma unroll
  for (int i = 0; i < 8; i++) {
    int u = tid + i * 256;
    if (u < 1920) {
      int row = u >> 6, x = u & 63;
      int c = row / 10, ry = row - c * 10;
      crop[c][ry][x + 1] = sv[i];
    }
  }
  __syncthreads();
  #pragma unroll
  for (int pr = 0; pr < 4; pr++) {
    float acc0[4] = {0.f, 0.f, 0.f, 0.f};
    float acc1[4] = {0.f, 0.f, 0.f, 0.f};
    #pragma unroll
    for (int c = 0; c < 3; c++) {
      #pragma unroll
      for (int r = 0; r < 4; r++) {
        const float* rp = &crop[c][2 * pr + r][4 * px];
        f32x4 v4 = *(const f32x4*)rp;               // 16B-aligned b128
        float2 v2 = *(const float2*)(rp + 4);       // 16B-aligned b64
        float in[6] = {v4[0], v4[1], v4[2], v4[3], v2.x, v2.y};
        if (r <= 2) {                               // conv row 0, kernel row r
          const float w0 = w[c * 9 + r * 3], w1 = w[c * 9 + r * 3 + 1],
                      w2 = w[c * 9 + r * 3 + 2];
          #pragma unroll
          for (int q = 0; q < 4; q++)
            acc0[q] += in[q] * w0 + in[q + 1] * w1 + in[q + 2] * w2;
        }
        if (r >= 1) {                               // conv row 1, kernel row r-1
          const float w0 = w[c * 9 + (r - 1) * 3], w1 = w[c * 9 + (r - 1) * 3 + 1],
                      w2 = w[c * 9 + (r - 1) * 3 + 2];
          #pragma unroll
          for (int q = 0; q < 4; q++)
            acc1[q] += in[q] * w0 + in[q + 1] * w1 + in[q + 2] * w2;
        }
      }
    }
    float m0 = fmaxf(fmaxf(acc0[0], acc0[1]), fmaxf(acc1[0], acc1[1]));
    float m1 = fmaxf(fmaxf(acc0[2], acc0[3]), fmaxf(acc1[2], acc1[3]));
    unsigned lo = f2bf(fmaxf(m0 + bias, 0.f));
    unsigned hi = f2bf(fmaxf(m1 + bias, 0.f));
    *(unsigned*)&feats[(size_t)det * 16384 + ch * 1024 + (pr0 + pr) * 32 + 2 * px] =
        lo | (hi << 16);
  }
}

// Fused FC1 GEMM (r10 structure -- best measured: 42us)
__global__ __launch_bounds__(512, 2) void k_gemm(const short* __restrict__ feats,
                                                 const float* __restrict__ W1,
                                                 float* __restrict__ part) {
  __shared__ __align__(16) short As[2][320 * 64];   // 81920 B
  int tid = threadIdx.x;
  int wid = tid >> 6, lane = tid & 63;
  int wm = wid & 3, wn = wid >> 2;          // 4 m-waves x 2 n-waves
  int lr = lane & 15, kg = lane >> 4;
  int ks = blockIdx.x, hd = blockIdx.y, dh = blockIdx.z;
  const int f0 = ks * 1024, d0 = dh * 64;
  const float* w1h = W1 + (size_t)hd * 16384 * 128;

  f32x4 acc[5][2];
  #pragma unroll
  for (int i = 0; i < 5; i++)
    #pragma unroll
    for (int j = 0; j < 2; j++) acc[i][j] = (f32x4){0.f, 0.f, 0.f, 0.f};

  // prologue: A tile 0 + B tile 0
  s16x8 aR[5];
  #pragma unroll
  for (int i = 0; i < 5; i++) {
    int ch = tid + i * 512, m = ch >> 3, c = ch & 7;
    aR[i] = *(const s16x8*)(feats + (size_t)m * 16384 + f0 + c * 8);
  }
  const float* bp = w1h + (size_t)(f0 + kg * 8) * 128 + d0 + wn * 32 + lr;
  float bF[2][2][8];
  #pragma unroll
  for (int k32 = 0; k32 < 2; k32++)
    #pragma unroll
    for (int nf = 0; nf < 2; nf++)
      #pragma unroll
      for (int j = 0; j < 8; j++)
        bF[k32][nf][j] = bp[(k32 * 32 + j) * 128 + nf * 16];
  #pragma unroll
  for (int i = 0; i < 5; i++) {
    int ch = tid + i * 512, m = ch >> 3, c = ch & 7;
    *(s16x8*)((char*)&As[0][0] + m * 128 + ((c ^ (m & 7)) << 4)) = aR[i];
  }
  __syncthreads();

  for (int t = 0; t < 16; ++t) {
    int cur = t & 1;
    s16x8 bfr[2][2];
    #pragma unroll
    for (int k32 = 0; k32 < 2; k32++)
      #pragma unroll
      for (int nf = 0; nf < 2; nf++)
        #pragma unroll
        for (int j = 0; j < 8; j++)
          bfr[k32][nf][j] = (short)f2bf(bF[k32][nf][j]);
    bool pf = (t + 1) < 16;
    if (pf) {                                 // issue next-tile loads early
      int f1 = f0 + (t + 1) * 64;
      #pragma unroll
      for (int i = 0; i < 5; i++) {
        int ch = tid + i * 512, m = ch >> 3, c = ch & 7;
        aR[i] = *(const s16x8*)(feats + (size_t)m * 16384 + f1 + c * 8);
      }
      const float* bp2 = bp + (size_t)(t + 1) * 64 * 128;
      #pragma unroll
      for (int k32 = 0; k32 < 2; k32++)
        #pragma unroll
        for (int nf = 0; nf < 2; nf++)
          #pragma unroll
          for (int j = 0; j < 8; j++)
            bF[k32][nf][j] = bp2[(k32 * 32 + j) * 128 + nf * 16];
    }
    #pragma unroll
    for (int k32 = 0; k32 < 2; ++k32) {
      s16x8 af[5];
      #pragma unroll
      for (int mf = 0; mf < 5; ++mf) {
        int row = wm * 80 + mf * 16 + lr;
        int c = k32 * 4 + kg;
        af[mf] = *(const s16x8*)((const char*)&As[cur][0] + row * 128 + ((c ^ (row & 7)) << 4));
      }
      #pragma unroll
      for (int nf = 0; nf < 2; ++nf)
        #pragma unroll
        for (int mf = 0; mf < 5; ++mf)
          acc[mf][nf] = __builtin_amdgcn_mfma_f32_16x16x32_bf16(af[mf], bfr[k32][nf], acc[mf][nf], 0, 0, 0);
    }
    if (pf) {                                 // write next tile (other buffer)
      #pragma unroll
      for (int i = 0; i < 5; i++) {
        int ch = tid + i * 512, m = ch >> 3, c = ch & 7;
        *(s16x8*)((char*)&As[cur ^ 1][0] + m * 128 + ((c ^ (m & 7)) << 4)) = aR[i];
      }
      __syncthreads();
    }
  }
  #pragma unroll
  for (int mf = 0; mf < 5; ++mf)
    #pragma unroll
    for (int nf = 0; nf < 2; ++nf)
      #pragma unroll
      for (int r = 0; r < 4; ++r) {
        int m = wm * 80 + mf * 16 + kg * 4 + r;   // C/D: row=(lane>>4)*4+r, col=lane&15
        int d = d0 + wn * 32 + nf * 16 + lr;
        part[(((size_t)ks * 8 + hd) * 320 + m) * 128 + d] = acc[mf][nf][r];
      }
}

// FC2 with inline split-K reduce: block per det; stage h[8][128] into LDS by
// summing 16 ksp partials + bias + relu, then the per-head matvecs.
__global__ __launch_bounds__(320) void k_fc2(const float* __restrict__ part,
                                             const float* __restrict__ b1,
                                             const float* __restrict__ keepf,
                                             const float* __restrict__ W2p,
                                             const float* __restrict__ b2p,
                                             const float* __restrict__ W2a,
                                             const float* __restrict__ b2a,
                                             const float* __restrict__ W2d,
                                             const float* __restrict__ b2d,
                                             float* __restrict__ out) {
  int det = blockIdx.x, t = threadIdx.x;
  __shared__ float hl[1024];
  for (int i = t; i < 1024; i += 320) {
    int hh = i >> 7, d = i & 127;
    float s = 0.f;
    #pragma unroll
    for (int ksp = 0; ksp < KSPLIT; ksp++)
      s += part[(((size_t)ksp * 8 + hh) * 320 + det) * 128 + d];
    hl[i] = fmaxf(s + b1[hh * 128 + d], 0.f);
  }
  __syncthreads();
  if (t >= 273) return;
  float kf = keepf[det];
  float s = 0.f, bias;
  if (t < 38) {
    const float* hp = hl;                        // head 0
    for (int d = 0; d < 128; d++) s += hp[d] * W2p[d * 38 + t];
    bias = b2p[t];
  } else if (t < 63) {
    int c = t - 38;
    const float* hp = hl + 128;                  // head 1
    for (int d = 0; d < 128; d++) s += hp[d] * W2a[d * 25 + c];
    bias = b2a[c];
  } else {
    int u = t - 63, j = u / 35, o = u - j * 35;
    const float* hp = hl + (2 + j) * 128;        // heads 2..7
    for (int d = 0; d < 128; d++) s += hp[d] * W2d[((size_t)j * 128 + d) * 35 + o];
    bias = b2d[j * 35 + o];
  }
  out[det * 273 + t] = (s + bias) * kf;
}

extern "C" void kernel_launch(void* const* d_in, const int* in_sizes, int n_in,
                              void* d_out, int out_size, void* d_ws, size_t ws_size,
                              hipStream_t stream) {
  (void)in_sizes; (void)n_in; (void)out_size; (void)ws_size;
  const float* preds = (const float*)d_in[0];
  const float* image = (const float*)d_in[1];
  const float* Wc    = (const float*)d_in[2];
  const float* bc    = (const float*)d_in[3];
  const float* W1    = (const float*)d_in[4];
  const float* b1    = (const float*)d_in[5];
  const float* W2p   = (const float*)d_in[6];
  const float* b2p   = (const float*)d_in[7];
  const float* W2a   = (const float*)d_in[8];
  const float* b2a   = (const float*)d_in[9];
  const float* W2d   = (const float*)d_in[10];
  const float* b2d   = (const float*)d_in[11];

  char* ws = (char*)d_ws;
  unsigned* hist   = (unsigned*)(ws + OFF_HIST);
  unsigned* cnt    = (unsigned*)(ws + OFF_CNT);
  u64*      cand   = (u64*)(ws + OFF_CAND);
  float*    boxes  = (float*)(ws + OFF_BOXES);
  int*      xy1    = (int*)(ws + OFF_XY1);
  float*    validf = (float*)(ws + OFF_VALID);
  float*    keepf  = (float*)(ws + OFF_KEEP);
  u64*      sup    = (u64*)(ws + OFF_SUP);
  short*    feats  = (short*)(ws + OFF_FEATS);
  float*    part   = (float*)(ws + OFF_PART);
  float*    out    = (float*)d_out;

  hipMemsetAsync(ws, 0, CTRL_BYTES, stream);
  k_hist<<<(N_PRED + 255) / 256, 256, 0, stream>>>(preds, hist);
  k_compact<<<(N_PRED + 255) / 256, 256, 0, stream>>>(preds, hist, cnt, cand);
  k_sortprep<<<1, 1024, 0, stream>>>(preds, cand, boxes, xy1, validf);
  k_iou<<<MAXD, 320, 0, stream>>>(boxes, sup);
  k_nms<<<1, 64, 0, stream>>>(sup, validf, keepf);
  k_cropconv<<<dim3(300, 8), 256, 0, stream>>>(image, Wc, bc, xy1, feats);
  k_gemm<<<dim3(KSPLIT, 8, 2), 512, 0, stream>>>(feats, W1, part);
  k_fc2<<<MAXD, 320, 0, stream>>>(part, b1, keepf, W2p, b2p, W2a, b2a, W2d, b2d, out);
}

// Round 22
// 119.314 us; speedup vs baseline: 1.1108x; 1.0050x over previous
//
#include <hip/hip_runtime.h>

#define N_PRED 25200
#define CONF 0.25f
#define IOU_THR 0.45f
#define MAXD 300
#define IMGW 640
#define CROPW 64
#define HISTN 16640
#define KSPLIT 16

typedef float f32x4 __attribute__((ext_vector_type(4)));
typedef short s16x8 __attribute__((ext_vector_type(8)));
typedef unsigned long long u64;

// ---- workspace layout (bytes) ----
#define OFF_HIST   0u            // 16640*4 = 66560
#define OFF_CNT    66560u        // counters (cnt at +0)
#define OFF_CAND   66816u        // 1024 * 8 = 8192
#define CTRL_BYTES 75008u        // memset [0, CTRL_BYTES) each call
#define OFF_BOXES  75008u        // 300*4*4
#define OFF_XY1    79872u        // 300*2*4
#define OFF_VALID  82432u        // 300*4
#define OFF_KEEP   83712u        // 300*4
#define OFF_SUP    84992u        // 300*5*8 = 12000
#define OFF_FEATS  1325824u      // 320*16384*2 = 10485760
#define OFF_PART   11811584u     // 16*8*320*128*4 = 26214400 (ends ~38MB)

__device__ inline unsigned short f2bf(float x) {
  unsigned u = __float_as_uint(x);
  u += 0x7FFFu + ((u >> 16) & 1u);   // round-to-nearest-even
  return (unsigned short)(u >> 16);
}

// ---------------- stage 1: score histogram (radix cut for top-300) -------
__global__ __launch_bounds__(256) void k_hist(const float* __restrict__ preds,
                                              unsigned* __restrict__ hist) {
  int i = blockIdx.x * 256 + threadIdx.x;
  if (i >= N_PRED) return;
  float s = preds[i * 6 + 4] * preds[i * 6 + 5];
  if (s > CONF) atomicAdd(&hist[__float_as_uint(s) >> 16], 1u);
}

// compact with INLINE findcut: every block recomputes the radix cut from
// hist (deterministic; parallel across blocks), then compacts its slice.
__global__ __launch_bounds__(256) void k_compact(const float* __restrict__ preds,
                                                 const unsigned* __restrict__ hist,
                                                 unsigned* __restrict__ cnt,
                                                 u64* __restrict__ cand) {
  __shared__ unsigned s[256];
  __shared__ unsigned scut;
  int t = threadIdx.x;
  int base = t * 65;                       // 256*65 = 16640
  unsigned local = 0;
  for (int i = 0; i < 65; ++i) local += hist[base + i];
  s[t] = local;
  __syncthreads();
  for (int off = 1; off < 256; off <<= 1) {   // inclusive suffix scan
    unsigned add = (t + off < 256) ? s[t + off] : 0u;
    __syncthreads();
    s[t] += add;
    __syncthreads();
  }
  unsigned incl = s[t];
  unsigned excl = (t < 255) ? s[t + 1] : 0u;
  if (t == 0) scut = 0u;
  __syncthreads();
  if (incl >= (unsigned)MAXD && excl < (unsigned)MAXD) {   // unique owner
    unsigned acc = excl, res = 0u;
    #pragma unroll
    for (int ii = 64; ii >= 0; --ii) {
      acc += hist[base + ii];
      if (res == 0u && acc >= (unsigned)MAXD) res = (unsigned)(base + ii);
    }
    scut = res;
  }
  __syncthreads();
  unsigned cutv = scut;

  int i = blockIdx.x * 256 + t;
  if (i >= N_PRED) return;
  float sc = preds[i * 6 + 4] * preds[i * 6 + 5];
  if (sc <= CONF) return;
  unsigned bits = __float_as_uint(sc);
  if ((bits >> 16) < cutv) return;
  unsigned pos = atomicAdd(cnt, 1u);
  if (pos < 1024u)
    cand[pos] = ((u64)bits << 32) | (u64)(0xFFFFFFFFu - (unsigned)i);  // ties: lower idx first
}

// bitonic sort 1024 u64 descending; emit boxes / crop coords / valid flags
__global__ __launch_bounds__(1024) void k_sortprep(const float* __restrict__ preds,
                                                   const u64* __restrict__ cand,
                                                   float* __restrict__ boxes,
                                                   int* __restrict__ xy1,
                                                   float* __restrict__ validf) {
  __shared__ u64 sk[1024];
  int t = threadIdx.x;
  sk[t] = cand[t];
  __syncthreads();
  for (int k = 2; k <= 1024; k <<= 1)
    for (int j = k >> 1; j > 0; j >>= 1) {
      int p = t ^ j;
      if (p > t) {
        u64 a = sk[t], b = sk[p];
        bool up = ((t & k) == 0);
        bool sw = up ? (a < b) : (a > b);      // descending overall
        if (sw) { sk[t] = b; sk[p] = a; }
      }
      __syncthreads();
    }
  if (t < MAXD) {
    u64 key = sk[t];
    if (key != 0ull) {
      int idx = (int)(0xFFFFFFFFu - (unsigned)(key & 0xFFFFFFFFull));
      float cx = preds[idx * 6 + 0], cy = preds[idx * 6 + 1];
      float w  = preds[idx * 6 + 2], h  = preds[idx * 6 + 3];
      float x1 = cx - w * 0.5f, y1 = cy - h * 0.5f;
      float x2 = cx + w * 0.5f, y2 = cy + h * 0.5f;
      boxes[t * 4 + 0] = x1; boxes[t * 4 + 1] = y1;
      boxes[t * 4 + 2] = x2; boxes[t * 4 + 3] = y2;
      int xi = (int)rintf(x1); xi = min(max(xi, 0), IMGW - CROPW);
      int yi = (int)rintf(y1); yi = min(max(yi, 0), IMGW - CROPW);
      xy1[t * 2 + 0] = xi; xy1[t * 2 + 1] = yi;
      validf[t] = 1.0f;
    } else {
      boxes[t * 4 + 0] = 0.f; boxes[t * 4 + 1] = 0.f;
      boxes[t * 4 + 2] = 0.f; boxes[t * 4 + 3] = 0.f;
      xy1[t * 2 + 0] = 0; xy1[t * 2 + 1] = 0;
      validf[t] = 0.f;
    }
  }
}

// parallel IoU suppression-mask build: block i = row i, thread t = column.
__global__ __launch_bounds__(320) void k_iou(const float* __restrict__ boxes,
                                             u64* __restrict__ sup) {
  int i = blockIdx.x, t = threadIdx.x;
  int w = t >> 6, lane = t & 63;
  f32x4 bi = *(const f32x4*)&boxes[i * 4];           // broadcast
  f32x4 bj = (t < MAXD) ? *(const f32x4*)&boxes[t * 4]
                        : (f32x4){0.f, 0.f, 0.f, 0.f};
  float ar  = (bi[2] - bi[0]) * (bi[3] - bi[1]);
  float arj = (bj[2] - bj[0]) * (bj[3] - bj[1]);
  float iw = fmaxf(fminf(bi[2], bj[2]) - fmaxf(bi[0], bj[0]), 0.f);
  float ih = fmaxf(fminf(bi[3], bj[3]) - fmaxf(bi[1], bj[1]), 0.f);
  float inter = iw * ih;
  float iou = inter / (ar + arj - inter + 1e-7f);
  u64 bm = __ballot((t < MAXD) && (iou > IOU_THR));
  if (lane == 0) sup[i * 5 + w] = bm;
}

// sequential greedy NMS, 1 wave: masks prefetched into registers, ff1 chain.
__global__ __launch_bounds__(64) void k_nms(const u64* __restrict__ sup,
                                            const float* __restrict__ validf,
                                            float* __restrict__ keepf) {
  int lane = threadIdx.x;
  u64 srow[5][5];
  #pragma unroll
  for (int c = 0; c < 5; ++c)
    #pragma unroll
    for (int ww = 0; ww < 5; ++ww) srow[c][ww] = 0ull;
  #pragma unroll
  for (int c = 0; c < 5; ++c) {
    int i = c * 64 + lane;
    if (i < MAXD) {
      #pragma unroll
      for (int ww = 0; ww <= c; ++ww) srow[c][ww] = sup[i * 5 + ww];
    }
  }
  u64 validm[5];
  #pragma unroll
  for (int c = 0; c < 5; ++c) {
    int i = c * 64 + lane;
    float vf = (i < MAXD) ? validf[i] : 0.f;
    validm[c] = __ballot(vf > 0.5f);
  }
  u64 kw0 = 0, kw1 = 0, kw2 = 0, kw3 = 0;
  #pragma unroll
  for (int c = 0; c < 5; ++c) {
    bool ext = ((srow[c][0] & kw0) | (srow[c][1] & kw1) |
                (srow[c][2] & kw2) | (srow[c][3] & kw3)) != 0ull;
    u64 alive = validm[c] & __ballot(!ext);
    unsigned mlo = (unsigned)srow[c][c], mhi = (unsigned)(srow[c][c] >> 32);
    u64 rem = alive;
    while (rem) {                           // rolled: only alive bits
      int b = (int)__builtin_ctzll(rem);
      u64 gt = (b == 63) ? 0ull : (~0ull << (b + 1));
      u64 mi = ((u64)(unsigned)__builtin_amdgcn_readlane((int)mhi, b) << 32) |
               (u64)(unsigned)__builtin_amdgcn_readlane((int)mlo, b);
      alive &= ~(mi & gt);
      rem = alive & gt;
    }
    int i = c * 64 + lane;
    if (i < MAXD) keepf[i] = ((alive >> lane) & 1ull) ? 1.f : 0.f;
    if (c == 0) kw0 = alive;
    else if (c == 1) kw1 = alive;
    else if (c == 2) kw2 = alive;
    else if (c == 3) kw3 = alive;
  }
}

// crop + 3x3 SAME conv(16) + ReLU + 2x2 maxpool -> feats[det][16384] (bf16)
// Grid (300, 8): det x 4-pooled-row slice. 256 thr = (ch 0..15) x (px 0..15).
__global__ __launch_bounds__(256) void k_cropconv(const float* __restrict__ image,
                                                  const float* __restrict__ Wc,
                                                  const float* __restrict__ bc,
                                                  const int* __restrict__ xy1,
                                                  short* __restrict__ feats) {
  __shared__ __align__(16) float crop[3][10][68];   // 8160 B
  int det = blockIdx.x, sl = blockIdx.y, tid = threadIdx.x;
  int pr0 = sl * 4;                 // pooled rows pr0..pr0+3
  int gyBase = pr0 * 2 - 1;         // global crop row of local ry=0 (10 rows)
  int ch = tid >> 4, px = tid & 15;

  float w[27];
  #pragma unroll
  for (int i = 0; i < 27; i++) w[i] = Wc[ch * 27 + i];
  float bias = bc[ch];

  int x0 = xy1[det * 2 + 0], y0 = xy1[det * 2 + 1];
  // register-stage 3*10*64 = 1920 elements (8 rounds of 256)
  float sv[8];
  #pragma unroll
  for (int i = 0; i < 8; i++) {
    int u = tid + i * 256;
    float v = 0.f;
    if (u < 1920) {
      int row = u >> 6, x = u & 63;
      int c = row / 10, ry = row - c * 10;
      int gy = gyBase + ry;
      if (gy >= 0 && gy < CROPW)
        v = image[(size_t)c * (IMGW * IMGW) + (y0 + gy) * IMGW + x0 + x];
    }
    sv[i] = v;
  }
  // zero the never-staged edge cells: cols {0,65,66,67} x 30 rows = 120
  if (tid < 120) {
    int row = tid >> 2, e = tid & 3;
    int c = row / 10, ry = row - c * 10;
    crop[c][ry][(e == 0) ? 0 : (64 + e)] = 0.f;
  }
  #pragma unroll
  for (int i = 0; i < 8; i++) {
    int u = tid + i * 256;
    if (u < 1920) {
      int row = u >> 6, x = u & 63;
      int c = row / 10, ry = row - c * 10;
      crop[c][ry][x + 1] = sv[i];
    }
  }
  __syncthreads();
  #pragma unroll
  for (int pr = 0; pr < 4; pr++) {
    float acc0[4] = {0.f, 0.f, 0.f, 0.f};
    float acc1[4] = {0.f, 0.f, 0.f, 0.f};
    #pragma unroll
    for (int c = 0; c < 3; c++) {
      #pragma unroll
      for (int r = 0; r < 4; r++) {
        const float* rp = &crop[c][2 * pr + r][4 * px];
        f32x4 v4 = *(const f32x4*)rp;               // 16B-aligned b128
        float2 v2 = *(const float2*)(rp + 4);       // 16B-aligned b64
        float in[6] = {v4[0], v4[1], v4[2], v4[3], v2.x, v2.y};
        if (r <= 2) {                               // conv row 0, kernel row r
          const float w0 = w[c * 9 + r * 3], w1 = w[c * 9 + r * 3 + 1],
                      w2 = w[c * 9 + r * 3 + 2];
          #pragma unroll
          for (int q = 0; q < 4; q++)
            acc0[q] += in[q] * w0 + in[q + 1] * w1 + in[q + 2] * w2;
        }
        if (r >= 1) {                               // conv row 1, kernel row r-1
          const float w0 = w[c * 9 + (r - 1) * 3], w1 = w[c * 9 + (r - 1) * 3 + 1],
                      w2 = w[c * 9 + (r - 1) * 3 + 2];
          #pragma unroll
          for (int q = 0; q < 4; q++)
            acc1[q] += in[q] * w0 + in[q + 1] * w1 + in[q + 2] * w2;
        }
      }
    }
    float m0 = fmaxf(fmaxf(acc0[0], acc0[1]), fmaxf(acc1[0], acc1[1]));
    float m1 = fmaxf(fmaxf(acc0[2], acc0[3]), fmaxf(acc1[2], acc1[3]));
    unsigned lo = f2bf(fmaxf(m0 + bias, 0.f));
    unsigned hi = f2bf(fmaxf(m1 + bias, 0.f));
    *(unsigned*)&feats[(size_t)det * 16384 + ch * 1024 + (pr0 + pr) * 32 + 2 * px] =
        lo | (hi << 16);
  }
}

// Fused FC1 GEMM (r10 structure, A-stage pipelined 2 tiles deep):
// at tile t the ds_write consumes A(t+1) loaded at t-1 (full-tile latency
// hiding); A(t+2) issued after the write. Same 2-buffer LDS aliasing as r10.
__global__ __launch_bounds__(512, 2) void k_gemm(const short* __restrict__ feats,
                                                 const float* __restrict__ W1,
                                                 float* __restrict__ part) {
  __shared__ __align__(16) short As[2][320 * 64];   // 81920 B
  int tid = threadIdx.x;
  int wid = tid >> 6, lane = tid & 63;
  int wm = wid & 3, wn = wid >> 2;          // 4 m-waves x 2 n-waves
  int lr = lane & 15, kg = lane >> 4;
  int ks = blockIdx.x, hd = blockIdx.y, dh = blockIdx.z;
  const int f0 = ks * 1024, d0 = dh * 64;
  const float* w1h = W1 + (size_t)hd * 16384 * 128;

  f32x4 acc[5][2];
  #pragma unroll
  for (int i = 0; i < 5; i++)
    #pragma unroll
    for (int j = 0; j < 2; j++) acc[i][j] = (f32x4){0.f, 0.f, 0.f, 0.f};

  // prologue: A(0) load+write (exposed once), then A(1) in flight; B(0).
  s16x8 aR[5];
  #pragma unroll
  for (int i = 0; i < 5; i++) {
    int ch = tid + i * 512, m = ch >> 3, c = ch & 7;
    aR[i] = *(const s16x8*)(feats + (size_t)m * 16384 + f0 + c * 8);
  }
  const float* bp = w1h + (size_t)(f0 + kg * 8) * 128 + d0 + wn * 32 + lr;
  float bF[2][2][8];
  #pragma unroll
  for (int k32 = 0; k32 < 2; k32++)
    #pragma unroll
    for (int nf = 0; nf < 2; nf++)
      #pragma unroll
      for (int j = 0; j < 8; j++)
        bF[k32][nf][j] = bp[(k32 * 32 + j) * 128 + nf * 16];
  #pragma unroll
  for (int i = 0; i < 5; i++) {
    int ch = tid + i * 512, m = ch >> 3, c = ch & 7;
    *(s16x8*)((char*)&As[0][0] + m * 128 + ((c ^ (m & 7)) << 4)) = aR[i];
  }
  // issue A(1) now -- consumed by ds_write at end of tile 0 (full tile away)
  #pragma unroll
  for (int i = 0; i < 5; i++) {
    int ch = tid + i * 512, m = ch >> 3, c = ch & 7;
    aR[i] = *(const s16x8*)(feats + (size_t)m * 16384 + f0 + 64 + c * 8);
  }
  __syncthreads();

  for (int t = 0; t < 16; ++t) {
    int cur = t & 1;
    s16x8 bfr[2][2];
    #pragma unroll
    for (int k32 = 0; k32 < 2; k32++)
      #pragma unroll
      for (int nf = 0; nf < 2; nf++)
        #pragma unroll
        for (int j = 0; j < 8; j++)
          bfr[k32][nf][j] = (short)f2bf(bF[k32][nf][j]);
    bool pf = (t + 1) < 16;
    if (pf) {                                 // issue next-tile B loads early
      const float* bp2 = bp + (size_t)(t + 1) * 64 * 128;
      #pragma unroll
      for (int k32 = 0; k32 < 2; k32++)
        #pragma unroll
        for (int nf = 0; nf < 2; nf++)
          #pragma unroll
          for (int j = 0; j < 8; j++)
            bF[k32][nf][j] = bp2[(k32 * 32 + j) * 128 + nf * 16];
    }
    #pragma unroll
    for (int k32 = 0; k32 < 2; ++k32) {
      s16x8 af[5];
      #pragma unroll
      for (int mf = 0; mf < 5; ++mf) {
        int row = wm * 80 + mf * 16 + lr;
        int c = k32 * 4 + kg;
        af[mf] = *(const s16x8*)((const char*)&As[cur][0] + row * 128 + ((c ^ (row & 7)) << 4));
      }
      #pragma unroll
      for (int nf = 0; nf < 2; ++nf)
        #pragma unroll
        for (int mf = 0; mf < 5; ++mf)
          acc[mf][nf] = __builtin_amdgcn_mfma_f32_16x16x32_bf16(af[mf], bfr[k32][nf], acc[mf][nf], 0, 0, 0);
    }
    if (pf) {
      // write A(t+1) from regs loaded one tile ago (latency hidden)
      #pragma unroll
      for (int i = 0; i < 5; i++) {
        int ch = tid + i * 512, m = ch >> 3, c = ch & 7;
        *(s16x8*)((char*)&As[cur ^ 1][0] + m * 128 + ((c ^ (m & 7)) << 4)) = aR[i];
      }
      if (t + 2 < 16) {                       // issue A(t+2), consumed next tile
        int f2 = f0 + (t + 2) * 64;
        #pragma unroll
        for (int i = 0; i < 5; i++) {
          int ch = tid + i * 512, m = ch >> 3, c = ch & 7;
          aR[i] = *(const s16x8*)(feats + (size_t)m * 16384 + f2 + c * 8);
        }
      }
      __syncthreads();
    }
  }
  #pragma unroll
  for (int mf = 0; mf < 5; ++mf)
    #pragma unroll
    for (int nf = 0; nf < 2; ++nf)
      #pragma unroll
      for (int r = 0; r < 4; ++r) {
        int m = wm * 80 + mf * 16 + kg * 4 + r;   // C/D: row=(lane>>4)*4+r, col=lane&15
        int d = d0 + wn * 32 + nf * 16 + lr;
        part[(((size_t)ks * 8 + hd) * 320 + m) * 128 + d] = acc[mf][nf][r];
      }
}

// FC2 with inline split-K reduce: block per det; stage h[8][128] into LDS by
// summing 16 ksp partials + bias + relu, then the per-head matvecs.
__global__ __launch_bounds__(320) void k_fc2(const float* __restrict__ part,
                                             const float* __restrict__ b1,
                                             const float* __restrict__ keepf,
                                             const float* __restrict__ W2p,
                                             const float* __restrict__ b2p,
                                             const float* __restrict__ W2a,
                                             const float* __restrict__ b2a,
                                             const float* __restrict__ W2d,
                                             const float* __restrict__ b2d,
                                             float* __restrict__ out) {
  int det = blockIdx.x, t = threadIdx.x;
  __shared__ float hl[1024];
  for (int i = t; i < 1024; i += 320) {
    int hh = i >> 7, d = i & 127;
    float s = 0.f;
    #pragma unroll
    for (int ksp = 0; ksp < KSPLIT; ksp++)
      s += part[(((size_t)ksp * 8 + hh) * 320 + det) * 128 + d];
    hl[i] = fmaxf(s + b1[hh * 128 + d], 0.f);
  }
  __syncthreads();
  if (t >= 273) return;
  float kf = keepf[det];
  float s = 0.f, bias;
  if (t < 38) {
    const float* hp = hl;                        // head 0
    for (int d = 0; d < 128; d++) s += hp[d] * W2p[d * 38 + t];
    bias = b2p[t];
  } else if (t < 63) {
    int c = t - 38;
    const float* hp = hl + 128;                  // head 1
    for (int d = 0; d < 128; d++) s += hp[d] * W2a[d * 25 + c];
    bias = b2a[c];
  } else {
    int u = t - 63, j = u / 35, o = u - j * 35;
    const float* hp = hl + (2 + j) * 128;        // heads 2..7
    for (int d = 0; d < 128; d++) s += hp[d] * W2d[((size_t)j * 128 + d) * 35 + o];
    bias = b2d[j * 35 + o];
  }
  out[det * 273 + t] = (s + bias) * kf;
}

extern "C" void kernel_launch(void* const* d_in, const int* in_sizes, int n_in,
                              void* d_out, int out_size, void* d_ws, size_t ws_size,
                              hipStream_t stream) {
  (void)in_sizes; (void)n_in; (void)out_size; (void)ws_size;
  const float* preds = (const float*)d_in[0];
  const float* image = (const float*)d_in[1];
  const float* Wc    = (const float*)d_in[2];
  const float* bc    = (const float*)d_in[3];
  const float* W1    = (const float*)d_in[4];
  const float* b1    = (const float*)d_in[5];
  const float* W2p   = (const float*)d_in[6];
  const float* b2p   = (const float*)d_in[7];
  const float* W2a   = (const float*)d_in[8];
  const float* b2a   = (const float*)d_in[9];
  const float* W2d   = (const float*)d_in[10];
  const float* b2d   = (const float*)d_in[11];

  char* ws = (char*)d_ws;
  unsigned* hist   = (unsigned*)(ws + OFF_HIST);
  unsigned* cnt    = (unsigned*)(ws + OFF_CNT);
  u64*      cand   = (u64*)(ws + OFF_CAND);
  float*    boxes  = (float*)(ws + OFF_BOXES);
  int*      xy1    = (int*)(ws + OFF_XY1);
  float*    validf = (float*)(ws + OFF_VALID);
  float*    keepf  = (float*)(ws + OFF_KEEP);
  u64*      sup    = (u64*)(ws + OFF_SUP);
  short*    feats  = (short*)(ws + OFF_FEATS);
  float*    part   = (float*)(ws + OFF_PART);
  float*    out    = (float*)d_out;

  hipMemsetAsync(ws, 0, CTRL_BYTES, stream);
  k_hist<<<(N_PRED + 255) / 256, 256, 0, stream>>>(preds, hist);
  k_compact<<<(N_PRED + 255) / 256, 256, 0, stream>>>(preds, hist, cnt, cand);
  k_sortprep<<<1, 1024, 0, stream>>>(preds, cand, boxes, xy1, validf);
  k_iou<<<MAXD, 320, 0, stream>>>(boxes, sup);
  k_nms<<<1, 64, 0, stream>>>(sup, validf, keepf);
  k_cropconv<<<dim3(300, 8), 256, 0, stream>>>(image, Wc, bc, xy1, feats);
  k_gemm<<<dim3(KSPLIT, 8, 2), 512, 0, stream>>>(feats, W1, part);
  k_fc2<<<MAXD, 320, 0, stream>>>(part, b1, keepf, W2p, b2p, W2a, b2a, W2d, b2d, out);
}

// Round 23
// 119.021 us; speedup vs baseline: 1.1136x; 1.0025x over previous
//
#include <hip/hip_runtime.h>

#define N_PRED 25200
#define CONF 0.25f
#define IOU_THR 0.45f
#define MAXD 300
#define IMGW 640
#define CROPW 64
#define HISTN 16640
#define KSPLIT 16

typedef float f32x4 __attribute__((ext_vector_type(4)));
typedef short s16x8 __attribute__((ext_vector_type(8)));
typedef unsigned long long u64;

// ---- workspace layout (bytes) ----
#define OFF_HIST   0u            // 16640*4 = 66560
#define OFF_CNT    66560u        // counters (cnt at +0)
#define OFF_CAND   66816u        // 1024 * 8 = 8192
#define CTRL_BYTES 75008u        // memset [0, CTRL_BYTES) each call
#define OFF_BOXES  75008u        // 300*4*4
#define OFF_XY1    79872u        // 300*2*4
#define OFF_VALID  82432u        // 300*4
#define OFF_KEEP   83712u        // 300*4
#define OFF_SUP    84992u        // 300*5*8 = 12000
#define OFF_FEATS  1325824u      // 320*16384*2 = 10485760
#define OFF_PART   11811584u     // 16*8*320*128*4 = 26214400 (ends ~38MB)

__device__ inline unsigned short f2bf(float x) {
  unsigned u = __float_as_uint(x);
  u += 0x7FFFu + ((u >> 16) & 1u);   // round-to-nearest-even
  return (unsigned short)(u >> 16);
}

// ---------------- stage 1: score histogram (radix cut for top-300) -------
__global__ __launch_bounds__(256) void k_hist(const float* __restrict__ preds,
                                              unsigned* __restrict__ hist) {
  int i = blockIdx.x * 256 + threadIdx.x;
  if (i >= N_PRED) return;
  float s = preds[i * 6 + 4] * preds[i * 6 + 5];
  if (s > CONF) atomicAdd(&hist[__float_as_uint(s) >> 16], 1u);
}

// compact with INLINE findcut: every block recomputes the radix cut from
// hist (deterministic; parallel across blocks), then compacts its slice.
__global__ __launch_bounds__(256) void k_compact(const float* __restrict__ preds,
                                                 const unsigned* __restrict__ hist,
                                                 unsigned* __restrict__ cnt,
                                                 u64* __restrict__ cand) {
  __shared__ unsigned s[256];
  __shared__ unsigned scut;
  int t = threadIdx.x;
  int base = t * 65;                       // 256*65 = 16640
  unsigned local = 0;
  for (int i = 0; i < 65; ++i) local += hist[base + i];
  s[t] = local;
  __syncthreads();
  for (int off = 1; off < 256; off <<= 1) {   // inclusive suffix scan
    unsigned add = (t + off < 256) ? s[t + off] : 0u;
    __syncthreads();
    s[t] += add;
    __syncthreads();
  }
  unsigned incl = s[t];
  unsigned excl = (t < 255) ? s[t + 1] : 0u;
  if (t == 0) scut = 0u;
  __syncthreads();
  if (incl >= (unsigned)MAXD && excl < (unsigned)MAXD) {   // unique owner
    unsigned acc = excl, res = 0u;
    #pragma unroll
    for (int ii = 64; ii >= 0; --ii) {
      acc += hist[base + ii];
      if (res == 0u && acc >= (unsigned)MAXD) res = (unsigned)(base + ii);
    }
    scut = res;
  }
  __syncthreads();
  unsigned cutv = scut;

  int i = blockIdx.x * 256 + t;
  if (i >= N_PRED) return;
  float sc = preds[i * 6 + 4] * preds[i * 6 + 5];
  if (sc <= CONF) return;
  unsigned bits = __float_as_uint(sc);
  if ((bits >> 16) < cutv) return;
  unsigned pos = atomicAdd(cnt, 1u);
  if (pos < 1024u)
    cand[pos] = ((u64)bits << 32) | (u64)(0xFFFFFFFFu - (unsigned)i);  // ties: lower idx first
}

// bitonic sort 1024 u64 descending; emit boxes / crop coords / valid flags
__global__ __launch_bounds__(1024) void k_sortprep(const float* __restrict__ preds,
                                                   const u64* __restrict__ cand,
                                                   float* __restrict__ boxes,
                                                   int* __restrict__ xy1,
                                                   float* __restrict__ validf) {
  __shared__ u64 sk[1024];
  int t = threadIdx.x;
  sk[t] = cand[t];
  __syncthreads();
  for (int k = 2; k <= 1024; k <<= 1)
    for (int j = k >> 1; j > 0; j >>= 1) {
      int p = t ^ j;
      if (p > t) {
        u64 a = sk[t], b = sk[p];
        bool up = ((t & k) == 0);
        bool sw = up ? (a < b) : (a > b);      // descending overall
        if (sw) { sk[t] = b; sk[p] = a; }
      }
      __syncthreads();
    }
  if (t < MAXD) {
    u64 key = sk[t];
    if (key != 0ull) {
      int idx = (int)(0xFFFFFFFFu - (unsigned)(key & 0xFFFFFFFFull));
      float cx = preds[idx * 6 + 0], cy = preds[idx * 6 + 1];
      float w  = preds[idx * 6 + 2], h  = preds[idx * 6 + 3];
      float x1 = cx - w * 0.5f, y1 = cy - h * 0.5f;
      float x2 = cx + w * 0.5f, y2 = cy + h * 0.5f;
      boxes[t * 4 + 0] = x1; boxes[t * 4 + 1] = y1;
      boxes[t * 4 + 2] = x2; boxes[t * 4 + 3] = y2;
      int xi = (int)rintf(x1); xi = min(max(xi, 0), IMGW - CROPW);
      int yi = (int)rintf(y1); yi = min(max(yi, 0), IMGW - CROPW);
      xy1[t * 2 + 0] = xi; xy1[t * 2 + 1] = yi;
      validf[t] = 1.0f;
    } else {
      boxes[t * 4 + 0] = 0.f; boxes[t * 4 + 1] = 0.f;
      boxes[t * 4 + 2] = 0.f; boxes[t * 4 + 3] = 0.f;
      xy1[t * 2 + 0] = 0; xy1[t * 2 + 1] = 0;
      validf[t] = 0.f;
    }
  }
}

// parallel IoU suppression-mask build: block i = row i, thread t = column.
__global__ __launch_bounds__(320) void k_iou(const float* __restrict__ boxes,
                                             u64* __restrict__ sup) {
  int i = blockIdx.x, t = threadIdx.x;
  int w = t >> 6, lane = t & 63;
  f32x4 bi = *(const f32x4*)&boxes[i * 4];           // broadcast
  f32x4 bj = (t < MAXD) ? *(const f32x4*)&boxes[t * 4]
                        : (f32x4){0.f, 0.f, 0.f, 0.f};
  float ar  = (bi[2] - bi[0]) * (bi[3] - bi[1]);
  float arj = (bj[2] - bj[0]) * (bj[3] - bj[1]);
  float iw = fmaxf(fminf(bi[2], bj[2]) - fmaxf(bi[0], bj[0]), 0.f);
  float ih = fmaxf(fminf(bi[3], bj[3]) - fmaxf(bi[1], bj[1]), 0.f);
  float inter = iw * ih;
  float iou = inter / (ar + arj - inter + 1e-7f);
  u64 bm = __ballot((t < MAXD) && (iou > IOU_THR));
  if (lane == 0) sup[i * 5 + w] = bm;
}

// sequential greedy NMS, 1 wave: masks prefetched into registers, ff1 chain.
__global__ __launch_bounds__(64) void k_nms(const u64* __restrict__ sup,
                                            const float* __restrict__ validf,
                                            float* __restrict__ keepf) {
  int lane = threadIdx.x;
  u64 srow[5][5];
  #pragma unroll
  for (int c = 0; c < 5; ++c)
    #pragma unroll
    for (int ww = 0; ww < 5; ++ww) srow[c][ww] = 0ull;
  #pragma unroll
  for (int c = 0; c < 5; ++c) {
    int i = c * 64 + lane;
    if (i < MAXD) {
      #pragma unroll
      for (int ww = 0; ww <= c; ++ww) srow[c][ww] = sup[i * 5 + ww];
    }
  }
  u64 validm[5];
  #pragma unroll
  for (int c = 0; c < 5; ++c) {
    int i = c * 64 + lane;
    float vf = (i < MAXD) ? validf[i] : 0.f;
    validm[c] = __ballot(vf > 0.5f);
  }
  u64 kw0 = 0, kw1 = 0, kw2 = 0, kw3 = 0;
  #pragma unroll
  for (int c = 0; c < 5; ++c) {
    bool ext = ((srow[c][0] & kw0) | (srow[c][1] & kw1) |
                (srow[c][2] & kw2) | (srow[c][3] & kw3)) != 0ull;
    u64 alive = validm[c] & __ballot(!ext);
    unsigned mlo = (unsigned)srow[c][c], mhi = (unsigned)(srow[c][c] >> 32);
    u64 rem = alive;
    while (rem) {                           // rolled: only alive bits
      int b = (int)__builtin_ctzll(rem);
      u64 gt = (b == 63) ? 0ull : (~0ull << (b + 1));
      u64 mi = ((u64)(unsigned)__builtin_amdgcn_readlane((int)mhi, b) << 32) |
               (u64)(unsigned)__builtin_amdgcn_readlane((int)mlo, b);
      alive &= ~(mi & gt);
      rem = alive & gt;
    }
    int i = c * 64 + lane;
    if (i < MAXD) keepf[i] = ((alive >> lane) & 1ull) ? 1.f : 0.f;
    if (c == 0) kw0 = alive;
    else if (c == 1) kw1 = alive;
    else if (c == 2) kw2 = alive;
    else if (c == 3) kw3 = alive;
  }
}

// crop + 3x3 SAME conv(16) + ReLU + 2x2 maxpool -> feats[det][16384] (bf16)
// Grid (300, 8): det x 4-pooled-row slice. 256 thr = (ch 0..15) x (px 0..15).
__global__ __launch_bounds__(256) void k_cropconv(const float* __restrict__ image,
                                                  const float* __restrict__ Wc,
                                                  const float* __restrict__ bc,
                                                  const int* __restrict__ xy1,
                                                  short* __restrict__ feats) {
  __shared__ __align__(16) float crop[3][10][68];   // 8160 B
  int det = blockIdx.x, sl = blockIdx.y, tid = threadIdx.x;
  int pr0 = sl * 4;                 // pooled rows pr0..pr0+3
  int gyBase = pr0 * 2 - 1;         // global crop row of local ry=0 (10 rows)
  int ch = tid >> 4, px = tid & 15;

  float w[27];
  #pragma unroll
  for (int i = 0; i < 27; i++) w[i] = Wc[ch * 27 + i];
  float bias = bc[ch];

  int x0 = xy1[det * 2 + 0], y0 = xy1[det * 2 + 1];
  // register-stage 3*10*64 = 1920 elements (8 rounds of 256)
  float sv[8];
  #pragma unroll
  for (int i = 0; i < 8; i++) {
    int u = tid + i * 256;
    float v = 0.f;
    if (u < 1920) {
      int row = u >> 6, x = u & 63;
      int c = row / 10, ry = row - c * 10;
      int gy = gyBase + ry;
      if (gy >= 0 && gy < CROPW)
        v = image[(size_t)c * (IMGW * IMGW) + (y0 + gy) * IMGW + x0 + x];
    }
    sv[i] = v;
  }
  // zero the never-staged edge cells: cols {0,65,66,67} x 30 rows = 120
  if (tid < 120) {
    int row = tid >> 2, e = tid & 3;
    int c = row / 10, ry = row - c * 10;
    crop[c][ry][(e == 0) ? 0 : (64 + e)] = 0.f;
  }
  #pragma unroll
  for (int i = 0; i < 8; i++) {
    int u = tid + i * 256;
    if (u < 1920) {
      int row = u >> 6, x = u & 63;
      int c = row / 10, ry = row - c * 10;
      crop[c][ry][x + 1] = sv[i];
    }
  }
  __syncthreads();
  #pragma unroll
  for (int pr = 0; pr < 4; pr++) {
    float acc0[4] = {0.f, 0.f, 0.f, 0.f};
    float acc1[4] = {0.f, 0.f, 0.f, 0.f};
    #pragma unroll
    for (int c = 0; c < 3; c++) {
      #pragma unroll
      for (int r = 0; r < 4; r++) {
        const float* rp = &crop[c][2 * pr + r][4 * px];
        f32x4 v4 = *(const f32x4*)rp;               // 16B-aligned b128
        float2 v2 = *(const float2*)(rp + 4);       // 16B-aligned b64
        float in[6] = {v4[0], v4[1], v4[2], v4[3], v2.x, v2.y};
        if (r <= 2) {                               // conv row 0, kernel row r
          const float w0 = w[c * 9 + r * 3], w1 = w[c * 9 + r * 3 + 1],
                      w2 = w[c * 9 + r * 3 + 2];
          #pragma unroll
          for (int q = 0; q < 4; q++)
            acc0[q] += in[q] * w0 + in[q + 1] * w1 + in[q + 2] * w2;
        }
        if (r >= 1) {                               // conv row 1, kernel row r-1
          const float w0 = w[c * 9 + (r - 1) * 3], w1 = w[c * 9 + (r - 1) * 3 + 1],
                      w2 = w[c * 9 + (r - 1) * 3 + 2];
          #pragma unroll
          for (int q = 0; q < 4; q++)
            acc1[q] += in[q] * w0 + in[q + 1] * w1 + in[q + 2] * w2;
        }
      }
    }
    float m0 = fmaxf(fmaxf(acc0[0], acc0[1]), fmaxf(acc1[0], acc1[1]));
    float m1 = fmaxf(fmaxf(acc0[2], acc0[3]), fmaxf(acc1[2], acc1[3]));
    unsigned lo = f2bf(fmaxf(m0 + bias, 0.f));
    unsigned hi = f2bf(fmaxf(m1 + bias, 0.f));
    *(unsigned*)&feats[(size_t)det * 16384 + ch * 1024 + (pr0 + pr) * 32 + 2 * px] =
        lo | (hi << 16);
  }
}

// Fused FC1 GEMM (r10 structure, A-stage pipelined 2 tiles deep):
// at tile t the ds_write consumes A(t+1) loaded at t-1 (full-tile latency
// hiding); A(t+2) issued after the write. Same 2-buffer LDS aliasing as r10.
__global__ __launch_bounds__(512, 2) void k_gemm(const short* __restrict__ feats,
                                                 const float* __restrict__ W1,
                                                 float* __restrict__ part) {
  __shared__ __align__(16) short As[2][320 * 64];   // 81920 B
  int tid = threadIdx.x;
  int wid = tid >> 6, lane = tid & 63;
  int wm = wid & 3, wn = wid >> 2;          // 4 m-waves x 2 n-waves
  int lr = lane & 15, kg = lane >> 4;
  int ks = blockIdx.x, hd = blockIdx.y, dh = blockIdx.z;
  const int f0 = ks * 1024, d0 = dh * 64;
  const float* w1h = W1 + (size_t)hd * 16384 * 128;

  f32x4 acc[5][2];
  #pragma unroll
  for (int i = 0; i < 5; i++)
    #pragma unroll
    for (int j = 0; j < 2; j++) acc[i][j] = (f32x4){0.f, 0.f, 0.f, 0.f};

  // prologue: A(0) load+write (exposed once), then A(1) in flight; B(0).
  s16x8 aR[5];
  #pragma unroll
  for (int i = 0; i < 5; i++) {
    int ch = tid + i * 512, m = ch >> 3, c = ch & 7;
    aR[i] = *(const s16x8*)(feats + (size_t)m * 16384 + f0 + c * 8);
  }
  const float* bp = w1h + (size_t)(f0 + kg * 8) * 128 + d0 + wn * 32 + lr;
  float bF[2][2][8];
  #pragma unroll
  for (int k32 = 0; k32 < 2; k32++)
    #pragma unroll
    for (int nf = 0; nf < 2; nf++)
      #pragma unroll
      for (int j = 0; j < 8; j++)
        bF[k32][nf][j] = bp[(k32 * 32 + j) * 128 + nf * 16];
  #pragma unroll
  for (int i = 0; i < 5; i++) {
    int ch = tid + i * 512, m = ch >> 3, c = ch & 7;
    *(s16x8*)((char*)&As[0][0] + m * 128 + ((c ^ (m & 7)) << 4)) = aR[i];
  }
  // issue A(1) now -- consumed by ds_write at end of tile 0 (full tile away)
  #pragma unroll
  for (int i = 0; i < 5; i++) {
    int ch = tid + i * 512, m = ch >> 3, c = ch & 7;
    aR[i] = *(const s16x8*)(feats + (size_t)m * 16384 + f0 + 64 + c * 8);
  }
  __syncthreads();

  for (int t = 0; t < 16; ++t) {
    int cur = t & 1;
    s16x8 bfr[2][2];
    #pragma unroll
    for (int k32 = 0; k32 < 2; k32++)
      #pragma unroll
      for (int nf = 0; nf < 2; nf++)
        #pragma unroll
        for (int j = 0; j < 8; j++)
          bfr[k32][nf][j] = (short)f2bf(bF[k32][nf][j]);
    bool pf = (t + 1) < 16;
    if (pf) {                                 // issue next-tile B loads early
      const float* bp2 = bp + (size_t)(t + 1) * 64 * 128;
      #pragma unroll
      for (int k32 = 0; k32 < 2; k32++)
        #pragma unroll
        for (int nf = 0; nf < 2; nf++)
          #pragma unroll
          for (int j = 0; j < 8; j++)
            bF[k32][nf][j] = bp2[(k32 * 32 + j) * 128 + nf * 16];
    }
    #pragma unroll
    for (int k32 = 0; k32 < 2; ++k32) {
      s16x8 af[5];
      #pragma unroll
      for (int mf = 0; mf < 5; ++mf) {
        int row = wm * 80 + mf * 16 + lr;
        int c = k32 * 4 + kg;
        af[mf] = *(const s16x8*)((const char*)&As[cur][0] + row * 128 + ((c ^ (row & 7)) << 4));
      }
      #pragma unroll
      for (int nf = 0; nf < 2; ++nf)
        #pragma unroll
        for (int mf = 0; mf < 5; ++mf)
          acc[mf][nf] = __builtin_amdgcn_mfma_f32_16x16x32_bf16(af[mf], bfr[k32][nf], acc[mf][nf], 0, 0, 0);
    }
    if (pf) {
      // write A(t+1) from regs loaded one tile ago (latency hidden)
      #pragma unroll
      for (int i = 0; i < 5; i++) {
        int ch = tid + i * 512, m = ch >> 3, c = ch & 7;
        *(s16x8*)((char*)&As[cur ^ 1][0] + m * 128 + ((c ^ (m & 7)) << 4)) = aR[i];
      }
      if (t + 2 < 16) {                       // issue A(t+2), consumed next tile
        int f2 = f0 + (t + 2) * 64;
        #pragma unroll
        for (int i = 0; i < 5; i++) {
          int ch = tid + i * 512, m = ch >> 3, c = ch & 7;
          aR[i] = *(const s16x8*)(feats + (size_t)m * 16384 + f2 + c * 8);
        }
      }
      __syncthreads();
    }
  }
  #pragma unroll
  for (int mf = 0; mf < 5; ++mf)
    #pragma unroll
    for (int nf = 0; nf < 2; ++nf)
      #pragma unroll
      for (int r = 0; r < 4; ++r) {
        int m = wm * 80 + mf * 16 + kg * 4 + r;   // C/D: row=(lane>>4)*4+r, col=lane&15
        int d = d0 + wn * 32 + nf * 16 + lr;
        part[(((size_t)ks * 8 + hd) * 320 + m) * 128 + d] = acc[mf][nf][r];
      }
}

// FC2 with inline split-K reduce: block per det; stage h[8][128] into LDS by
// summing 16 ksp partials + bias + relu, then the per-head matvecs.
__global__ __launch_bounds__(320) void k_fc2(const float* __restrict__ part,
                                             const float* __restrict__ b1,
                                             const float* __restrict__ keepf,
                                             const float* __restrict__ W2p,
                                             const float* __restrict__ b2p,
                                             const float* __restrict__ W2a,
                                             const float* __restrict__ b2a,
                                             const float* __restrict__ W2d,
                                             const float* __restrict__ b2d,
                                             float* __restrict__ out) {
  int det = blockIdx.x, t = threadIdx.x;
  __shared__ float hl[1024];
  for (int i = t; i < 1024; i += 320) {
    int hh = i >> 7, d = i & 127;
    float s = 0.f;
    #pragma unroll
    for (int ksp = 0; ksp < KSPLIT; ksp++)
      s += part[(((size_t)ksp * 8 + hh) * 320 + det) * 128 + d];
    hl[i] = fmaxf(s + b1[hh * 128 + d], 0.f);
  }
  __syncthreads();
  if (t >= 273) return;
  float kf = keepf[det];
  float s = 0.f, bias;
  if (t < 38) {
    const float* hp = hl;                        // head 0
    for (int d = 0; d < 128; d++) s += hp[d] * W2p[d * 38 + t];
    bias = b2p[t];
  } else if (t < 63) {
    int c = t - 38;
    const float* hp = hl + 128;                  // head 1
    for (int d = 0; d < 128; d++) s += hp[d] * W2a[d * 25 + c];
    bias = b2a[c];
  } else {
    int u = t - 63, j = u / 35, o = u - j * 35;
    const float* hp = hl + (2 + j) * 128;        // heads 2..7
    for (int d = 0; d < 128; d++) s += hp[d] * W2d[((size_t)j * 128 + d) * 35 + o];
    bias = b2d[j * 35 + o];
  }
  out[det * 273 + t] = (s + bias) * kf;
}

extern "C" void kernel_launch(void* const* d_in, const int* in_sizes, int n_in,
                              void* d_out, int out_size, void* d_ws, size_t ws_size,
                              hipStream_t stream) {
  (void)in_sizes; (void)n_in; (void)out_size; (void)ws_size;
  const float* preds = (const float*)d_in[0];
  const float* image = (const float*)d_in[1];
  const float* Wc    = (const float*)d_in[2];
  const float* bc    = (const float*)d_in[3];
  const float* W1    = (const float*)d_in[4];
  const float* b1    = (const float*)d_in[5];
  const float* W2p   = (const float*)d_in[6];
  const float* b2p   = (const float*)d_in[7];
  const float* W2a   = (const float*)d_in[8];
  const float* b2a   = (const float*)d_in[9];
  const float* W2d   = (const float*)d_in[10];
  const float* b2d   = (const float*)d_in[11];

  char* ws = (char*)d_ws;
  unsigned* hist   = (unsigned*)(ws + OFF_HIST);
  unsigned* cnt    = (unsigned*)(ws + OFF_CNT);
  u64*      cand   = (u64*)(ws + OFF_CAND);
  float*    boxes  = (float*)(ws + OFF_BOXES);
  int*      xy1    = (int*)(ws + OFF_XY1);
  float*    validf = (float*)(ws + OFF_VALID);
  float*    keepf  = (float*)(ws + OFF_KEEP);
  u64*      sup    = (u64*)(ws + OFF_SUP);
  short*    feats  = (short*)(ws + OFF_FEATS);
  float*    part   = (float*)(ws + OFF_PART);
  float*    out    = (float*)d_out;

  hipMemsetAsync(ws, 0, CTRL_BYTES, stream);
  k_hist<<<(N_PRED + 255) / 256, 256, 0, stream>>>(preds, hist);
  k_compact<<<(N_PRED + 255) / 256, 256, 0, stream>>>(preds, hist, cnt, cand);
  k_sortprep<<<1, 1024, 0, stream>>>(preds, cand, boxes, xy1, validf);
  k_iou<<<MAXD, 320, 0, stream>>>(boxes, sup);
  k_nms<<<1, 64, 0, stream>>>(sup, validf, keepf);
  k_cropconv<<<dim3(300, 8), 256, 0, stream>>>(image, Wc, bc, xy1, feats);
  k_gemm<<<dim3(KSPLIT, 8, 2), 512, 0, stream>>>(feats, W1, part);
  k_fc2<<<MAXD, 320, 0, stream>>>(part, b1, keepf, W2p, b2p, W2a, b2a, W2d, b2d, out);
}